// Round 1
// baseline (182.751 us; speedup 1.0000x reference)
//
#include <hip/hip_runtime.h>

// Depthwise 4x4 FIR blur, pad (2,2)/(2,2), NCHW fp32.
// x: [16,256,128,128] -> out: [16,256,129,129]
// Each thread: 4 output cols (J = 4t-2 .. 4t+1, t in [0,32]) x 32 output rows
// (chunk c in [0,3]; c==3 also does row 128). Register ring of 4 input rows,
// 8 floats wide (two aligned float4 loads per row).

__global__ __launch_bounds__(256) void blur_fir_kernel(
    const float* __restrict__ x,
    const float* __restrict__ kern,
    float* __restrict__ out)
{
    const int gtid = blockIdx.x * 256 + threadIdx.x;
    // 132 tasks per image: c (row-chunk 0..3) * t (col-group 0..32)
    const int img = gtid / 132;
    const int rem = gtid - img * 132;
    const int c   = rem / 33;
    const int t   = rem - c * 33;

    // 4x4 weights; uniform address -> scalar loads -> SGPRs
    float w[4][4];
#pragma unroll
    for (int p = 0; p < 4; ++p)
#pragma unroll
        for (int q = 0; q < 4; ++q)
            w[p][q] = kern[4 * p + q];

    const float* __restrict__ xi = x + (size_t)img * (128 * 128);
    float* __restrict__ oi = out + (size_t)img * (129 * 129);

    const int  i0   = c * 32;        // first output row of this chunk
    const int  col0 = 4 * t - 4;     // input col of xv[.][0]
    const bool lv   = (t >= 1);      // left  float4 (cols 4t-4..4t-1) in-bounds
    const bool rv   = (t <= 31);     // right float4 (cols 4t..4t+3)  in-bounds

    float xv[4][8];                  // ring: 4 input rows x 8 cols, all static idx

#define LOADROW(S, R) do {                                                   \
        const int   r_   = (R);                                              \
        const bool  okr_ = (r_ >= 0) && (r_ < 128);                          \
        const float* p_  = xi + r_ * 128 + col0;                             \
        float4 a_ = make_float4(0.f, 0.f, 0.f, 0.f);                         \
        float4 b_ = make_float4(0.f, 0.f, 0.f, 0.f);                         \
        if (okr_ && lv) a_ = *(const float4*)p_;                             \
        if (okr_ && rv) b_ = *(const float4*)(p_ + 4);                       \
        xv[S][0] = a_.x; xv[S][1] = a_.y; xv[S][2] = a_.z; xv[S][3] = a_.w;  \
        xv[S][4] = b_.x; xv[S][5] = b_.y; xv[S][6] = b_.z; xv[S][7] = b_.w;  \
    } while (0)

    // out col J = 4t-2+o uses input cols J-2..J+1 = xv idx o..o+3
#define ACCP(S, P) do {                                                      \
        o0 = fmaf(xv[S][0], w[P][0], o0);                                    \
        o1 = fmaf(xv[S][1], w[P][0], o1);                                    \
        o2 = fmaf(xv[S][2], w[P][0], o2);                                    \
        o3 = fmaf(xv[S][3], w[P][0], o3);                                    \
        o0 = fmaf(xv[S][1], w[P][1], o0);                                    \
        o1 = fmaf(xv[S][2], w[P][1], o1);                                    \
        o2 = fmaf(xv[S][3], w[P][1], o2);                                    \
        o3 = fmaf(xv[S][4], w[P][1], o3);                                    \
        o0 = fmaf(xv[S][2], w[P][2], o0);                                    \
        o1 = fmaf(xv[S][3], w[P][2], o1);                                    \
        o2 = fmaf(xv[S][4], w[P][2], o2);                                    \
        o3 = fmaf(xv[S][5], w[P][2], o3);                                    \
        o0 = fmaf(xv[S][3], w[P][3], o0);                                    \
        o1 = fmaf(xv[S][4], w[P][3], o1);                                    \
        o2 = fmaf(xv[S][5], w[P][3], o2);                                    \
        o3 = fmaf(xv[S][6], w[P][3], o3);                                    \
    } while (0)

    // J = 4t-2: po[0],po[1] invalid iff t==0; po[2] (J=4t<=128) always ok;
    // po[3] (J=4t+1) invalid iff t==32.
#define COMPUTE_STORE(SA, SB, SC, SD, PO) do {                               \
        float o0 = 0.f, o1 = 0.f, o2 = 0.f, o3 = 0.f;                        \
        ACCP(SA, 0); ACCP(SB, 1); ACCP(SC, 2); ACCP(SD, 3);                  \
        if (lv) { (PO)[0] = o0; (PO)[1] = o1; }                              \
        (PO)[2] = o2;                                                        \
        if (rv) { (PO)[3] = o3; }                                            \
    } while (0)

    // Preload rows i0-2 .. i0+1 into slots (row & 3); i0 % 4 == 0.
    LOADROW(2, i0 - 2);
    LOADROW(3, i0 - 1);
    LOADROW(0, i0 + 0);
    LOADROW(1, i0 + 1);

    float* po = oi + (size_t)i0 * 129 + (4 * t - 2);

    for (int ii = 0; ii < 32; ii += 4) {
        const int i = i0 + ii;
        // step u: compute row i+u (slots (u+2)&3,(u+3)&3,u&3,(u+1)&3), then
        // load row i+u+2 into slot (u+2)&3 (its old row i+u-2 is done).
        COMPUTE_STORE(2, 3, 0, 1, po); LOADROW(2, i + 2); po += 129;
        COMPUTE_STORE(3, 0, 1, 2, po); LOADROW(3, i + 3); po += 129;
        COMPUTE_STORE(0, 1, 2, 3, po); LOADROW(0, i + 4); po += 129;
        COMPUTE_STORE(1, 2, 3, 0, po); LOADROW(1, i + 5); po += 129;
    }

    // Output row 128 (only chunk 3): needs input rows 126..129.
    // Ring now holds: slot2=row126, slot3=row127, slot0=zeros(row128),
    // slot1=zeros(row129) -- both loads were range-guarded to zero.
    if (c == 3) {
        COMPUTE_STORE(2, 3, 0, 1, po);
    }

#undef LOADROW
#undef ACCP
#undef COMPUTE_STORE
}

extern "C" void kernel_launch(void* const* d_in, const int* in_sizes, int n_in,
                              void* d_out, int out_size, void* d_ws, size_t ws_size,
                              hipStream_t stream) {
    const float* x    = (const float*)d_in[0];
    const float* kern = (const float*)d_in[1];
    float* out        = (float*)d_out;

    // 4096 images * 132 threads/image = 540,672 = 2112 * 256 exactly
    dim3 grid(2112), block(256);
    hipLaunchKernelGGL(blur_fir_kernel, grid, block, 0, stream, x, kern, out);
}

// Round 2
// 116.381 us; speedup vs baseline: 1.5703x; 1.5703x over previous
//
#include <hip/hip_runtime.h>

// Depthwise 4x4 FIR blur, pad (2,2)/(2,2), NCHW fp32.
// x: [16,256,128,128] -> out: [16,256,129,129]
//
// Block (256 thr) = one 32-output-row strip of one image (strip 3: 33 rows).
// Stage 36 input rows (18 KB) into LDS via global_load_lds (1 KB/instr,
// 17-18 instrs per block, deep MLP). Compute: thread = 4 output cols x 4
// output rows, register ring of 4 LDS rows read as 2x ds_read_b128.
// Cols 126..128 (the 129 = 32*4+1 leftover) done by lanes 0..7 of wave 0.

#define LDSROWS 36

__global__ __launch_bounds__(256) void blur_fir_lds(
    const float* __restrict__ x,
    const float* __restrict__ kern,
    float* __restrict__ out)
{
    __shared__ __align__(16) float lds[LDSROWS * 128];

    const int tid = threadIdx.x;
    const int bid = blockIdx.x;
    const int img = bid >> 2;       // 4096 images
    const int s   = bid & 3;        // strip 0..3
    const int wv  = tid >> 6;
    const int lane = tid & 63;

    const float* __restrict__ xi = x + (size_t)img * (128 * 128);
    float* __restrict__ oi = out + (size_t)img * (129 * 129);

    // LDS slot k holds input row (lstart + k); rows outside [0,127] are zeros.
    const int lstart = 32 * s - 2;
    const int vs     = (s == 0) ? 0 : lstart;     // first valid input row staged
    const int slot0  = vs - lstart;               // 2 for s==0 else 0
    const int nrows  = (s == 0 || s == 3) ? 34 : 36;
    const int nch    = nrows >> 1;                // 1 KB chunks (2 rows each)

    // ---- stage: deep burst of global_load_lds (16B/lane, 1KB/instr) ----
    for (int k = wv; k < nch; k += 4) {
        const float* src = xi + (size_t)(vs + 2 * k) * 128 + lane * 4;
        const float* dst = &lds[(slot0 + 2 * k) * 128];
        __builtin_amdgcn_global_load_lds(
            (const __attribute__((address_space(1))) unsigned int*)src,
            (__attribute__((address_space(3))) unsigned int*)(dst), 16, 0, 0);
    }
    // zero-pad edge slots (disjoint from staged region)
    if (s == 0) lds[tid] = 0.0f;              // slots 0,1  (rows -2,-1)
    if (s == 3) lds[34 * 128 + tid] = 0.0f;   // slots 34,35 (rows 128,129)

    // 4x4 weights; uniform -> SGPRs
    float w[4][4];
#pragma unroll
    for (int p = 0; p < 4; ++p)
#pragma unroll
        for (int q = 0; q < 4; ++q)
            w[p][q] = kern[4 * p + q];

    __syncthreads();

    // ---- compute ----
    const int c = tid >> 5;         // row-subchunk 0..7 (4 rows each)
    const int t = tid & 31;         // col-group: out cols J = 4t-2 .. 4t+1
    const bool lv = (t >= 1);       // left float4 (cols 4t-4..4t-1) valid

    float xv[4][8];

#define LLOAD(S, SLOT) do {                                                  \
        const float* p_ = &lds[(SLOT) * 128 + 4 * t - 4];                    \
        float4 a_ = make_float4(0.f, 0.f, 0.f, 0.f);                         \
        if (lv) a_ = *(const float4*)p_;                                     \
        float4 b_ = *(const float4*)(p_ + 4);                                \
        xv[S][0] = a_.x; xv[S][1] = a_.y; xv[S][2] = a_.z; xv[S][3] = a_.w;  \
        xv[S][4] = b_.x; xv[S][5] = b_.y; xv[S][6] = b_.z; xv[S][7] = b_.w;  \
    } while (0)

#define ACCP(S, P) do {                                                      \
        o0 = fmaf(xv[S][0], w[P][0], o0);                                    \
        o1 = fmaf(xv[S][1], w[P][0], o1);                                    \
        o2 = fmaf(xv[S][2], w[P][0], o2);                                    \
        o3 = fmaf(xv[S][3], w[P][0], o3);                                    \
        o0 = fmaf(xv[S][1], w[P][1], o0);                                    \
        o1 = fmaf(xv[S][2], w[P][1], o1);                                    \
        o2 = fmaf(xv[S][3], w[P][1], o2);                                    \
        o3 = fmaf(xv[S][4], w[P][1], o3);                                    \
        o0 = fmaf(xv[S][2], w[P][2], o0);                                    \
        o1 = fmaf(xv[S][3], w[P][2], o1);                                    \
        o2 = fmaf(xv[S][4], w[P][2], o2);                                    \
        o3 = fmaf(xv[S][5], w[P][2], o3);                                    \
        o0 = fmaf(xv[S][3], w[P][3], o0);                                    \
        o1 = fmaf(xv[S][4], w[P][3], o1);                                    \
        o2 = fmaf(xv[S][5], w[P][3], o2);                                    \
        o3 = fmaf(xv[S][6], w[P][3], o3);                                    \
    } while (0)

#define COMPUTE_STORE(SA, SB, SC, SD, PO) do {                               \
        float o0 = 0.f, o1 = 0.f, o2 = 0.f, o3 = 0.f;                        \
        ACCP(SA, 0); ACCP(SB, 1); ACCP(SC, 2); ACCP(SD, 3);                  \
        if (lv) { (PO)[0] = o0; (PO)[1] = o1; }                              \
        (PO)[2] = o2;                                                        \
        (PO)[3] = o3;                                                        \
    } while (0)

    {
        const int R0 = 32 * s + 4 * c;
        float* po = oi + (size_t)R0 * 129 + (4 * t - 2);
        LLOAD(0, 4 * c + 0); LLOAD(1, 4 * c + 1);
        LLOAD(2, 4 * c + 2); LLOAD(3, 4 * c + 3);
        COMPUTE_STORE(0, 1, 2, 3, po); LLOAD(0, 4 * c + 4); po += 129;
        COMPUTE_STORE(1, 2, 3, 0, po); LLOAD(1, 4 * c + 5); po += 129;
        COMPUTE_STORE(2, 3, 0, 1, po); LLOAD(2, 4 * c + 6); po += 129;
        COMPUTE_STORE(3, 0, 1, 2, po); po += 129;
        if (s == 3 && c == 7) {                  // output row 128
            LLOAD(3, 35);
            COMPUTE_STORE(0, 1, 2, 3, po);
        }
    }

    // ---- leftover cols 126..128 (window cols 124..129; 128,129 are zero) ----
    if (tid < 8) {
        const int c2 = tid;
#define LLOAD2(S, SLOT) do {                                                 \
        float4 a_ = *(const float4*)&lds[(SLOT) * 128 + 124];                \
        xv[S][0] = a_.x; xv[S][1] = a_.y; xv[S][2] = a_.z; xv[S][3] = a_.w;  \
        xv[S][4] = 0.f; xv[S][5] = 0.f; xv[S][6] = 0.f; xv[S][7] = 0.f;      \
    } while (0)

#define COMPUTE_STORE2(SA, SB, SC, SD, PO) do {                              \
        float o0 = 0.f, o1 = 0.f, o2 = 0.f, o3 = 0.f;                        \
        ACCP(SA, 0); ACCP(SB, 1); ACCP(SC, 2); ACCP(SD, 3);                  \
        (PO)[0] = o0; (PO)[1] = o1; (PO)[2] = o2; (void)o3;                  \
    } while (0)

        const int R0 = 32 * s + 4 * c2;
        float* po = oi + (size_t)R0 * 129 + 126;
        LLOAD2(0, 4 * c2 + 0); LLOAD2(1, 4 * c2 + 1);
        LLOAD2(2, 4 * c2 + 2); LLOAD2(3, 4 * c2 + 3);
        COMPUTE_STORE2(0, 1, 2, 3, po); LLOAD2(0, 4 * c2 + 4); po += 129;
        COMPUTE_STORE2(1, 2, 3, 0, po); LLOAD2(1, 4 * c2 + 5); po += 129;
        COMPUTE_STORE2(2, 3, 0, 1, po); LLOAD2(2, 4 * c2 + 6); po += 129;
        COMPUTE_STORE2(3, 0, 1, 2, po); po += 129;
        if (s == 3 && c2 == 7) {                 // row 128, cols 126..128
            LLOAD2(3, 35);
            COMPUTE_STORE2(0, 1, 2, 3, po);
        }
    }

#undef LLOAD
#undef LLOAD2
#undef ACCP
#undef COMPUTE_STORE
#undef COMPUTE_STORE2
}

extern "C" void kernel_launch(void* const* d_in, const int* in_sizes, int n_in,
                              void* d_out, int out_size, void* d_ws, size_t ws_size,
                              hipStream_t stream) {
    const float* x    = (const float*)d_in[0];
    const float* kern = (const float*)d_in[1];
    float* out        = (float*)d_out;

    // 4096 images * 4 strips = 16384 blocks
    dim3 grid(16384), block(256);
    hipLaunchKernelGGL(blur_fir_lds, grid, block, 0, stream, x, kern, out);
}